// Round 4
// baseline (598.642 us; speedup 1.0000x reference)
//
#include <hip/hip_runtime.h>
#include <hip/hip_bf16.h>

#define NPIX 6400
#define IMW 80
#define IMH 80

typedef __attribute__((ext_vector_type(8))) short short8;
typedef __attribute__((ext_vector_type(4))) float floatx4;

__device__ __forceinline__ float silu_f(float v) {
    return v / (1.0f + __expf(-v));
}
__device__ __forceinline__ unsigned short f2bf(float v) {
    __hip_bfloat16 h = __float2bfloat16(v);
    return *(unsigned short*)&h;
}

// ---------------- prep: W1 [256][256], W2 [256][384] fp32 -> bf16 ----------------
__global__ __launch_bounds__(256) void prep_small(
    const float* __restrict__ W1, const float* __restrict__ W2,
    __hip_bfloat16* __restrict__ Wt1, __hip_bfloat16* __restrict__ Wt2)
{
    int i = blockIdx.x * 256 + threadIdx.x;
    if (i < 65536) Wt1[i] = __float2bfloat16(W1[i]);
    if (i < 98304) Wt2[i] = __float2bfloat16(W2[i]);
}

// ---------------- prep: W_exp fp32 [e][co][ci][3][3] -> Wt bf16 [e][co][tap*128+ci] -------
__global__ __launch_bounds__(256) void prep_wt(
    const float* __restrict__ Wexp, __hip_bfloat16* __restrict__ Wt)
{
    int idx = blockIdx.x * 256 + threadIdx.x;   // e*16384 + co*128 + ci
    const float* src = Wexp + (size_t)idx * 9;
    int e  = idx >> 14;
    int rem = idx & 16383;
    int co = rem >> 7, ci = rem & 127;
    __hip_bfloat16* dst = Wt + ((size_t)(e * 128 + co)) * 1152 + ci;
    #pragma unroll
    for (int tap = 0; tap < 9; ++tap)
        dst[tap * 128] = __float2bfloat16(src[tap]);
}

// ---------------- transpose x [b][ci][pix] fp32 -> catT[b][pix][ci] bf16 (slots 0..255) ----
__global__ __launch_bounds__(256) void transpose_x(
    const float* __restrict__ x, __hip_bfloat16* __restrict__ catT)
{
    const int b   = blockIdx.z;
    const int ci0 = blockIdx.y * 64;
    const int p0  = blockIdx.x * 64;
    __shared__ unsigned short t[64][70];   // [pix][ci], stride 70 (70/2=35 odd -> conflict-light)
    const int tid = threadIdx.x;
    const float* src = x + ((size_t)b * 256 + ci0) * NPIX + p0;
    #pragma unroll
    for (int it = 0; it < 4; ++it) {
        int idx = tid + it * 256;          // 0..1023
        int ci = idx >> 4, pg = idx & 15;
        float4 v = *(const float4*)(src + (size_t)ci * NPIX + pg * 4);
        t[pg * 4 + 0][ci] = f2bf(v.x);
        t[pg * 4 + 1][ci] = f2bf(v.y);
        t[pg * 4 + 2][ci] = f2bf(v.z);
        t[pg * 4 + 3][ci] = f2bf(v.w);
    }
    __syncthreads();
    unsigned short* dst = (unsigned short*)catT + ((size_t)b * NPIX + p0) * 384 + ci0;
    #pragma unroll
    for (int it = 0; it < 4; ++it) {
        int idx = tid + it * 256;
        int p = idx >> 4, cg = idx & 15;
        unsigned short vv[4];
        #pragma unroll
        for (int j = 0; j < 4; ++j) vv[j] = t[p][cg * 4 + j];
        *(uint2*)(dst + (size_t)p * 384 + cg * 4) = *(uint2*)vv;
    }
}

// ---------------- cv1 as MFMA GEMM, in-place on catT --------------------------------------
// catT[pix][0..255] holds bf16(x) on entry; overwritten with silu(W1@x+b1) in epilogue.
// grid (100 pix-chunks, 16 b), block 256 = 4 waves (2 co-halves x 2 pix-halves); K=256
__global__ __launch_bounds__(256) void cv1_mfma(
    const __hip_bfloat16* __restrict__ Wt1, const float* __restrict__ b1,
    __hip_bfloat16* __restrict__ catT, float* __restrict__ pooled)
{
    const int b  = blockIdx.y;
    const int p0 = blockIdx.x * 64;
    const int tid = threadIdx.x;
    const int wave = tid >> 6, lane = tid & 63;
    const int col = lane & 15, quad = lane >> 4;
    const int cohalf = (wave >> 1) * 128;   // 0 / 128
    const int wpx    = (wave & 1) * 32;     // 0 / 32

    __hip_bfloat16* ct = catT + (size_t)b * NPIX * 384;
    int pp[2];
    pp[0] = p0 + wpx + col;
    pp[1] = pp[0] + 16;

    floatx4 acc[8][2] = {};

    for (int k0 = 0; k0 < 256; k0 += 32) {
        short8 bf[2];
        #pragma unroll
        for (int nt = 0; nt < 2; ++nt)
            bf[nt] = *(const short8*)&ct[(size_t)pp[nt] * 384 + k0 + quad * 8];
        #pragma unroll
        for (int mt = 0; mt < 8; ++mt) {
            short8 af = *(const short8*)&Wt1[(size_t)(cohalf + mt * 16 + col) * 256
                                             + k0 + quad * 8];
            acc[mt][0] = __builtin_amdgcn_mfma_f32_16x16x32_bf16(af, bf[0], acc[mt][0], 0, 0, 0);
            acc[mt][1] = __builtin_amdgcn_mfma_f32_16x16x32_bf16(af, bf[1], acc[mt][1], 0, 0, 0);
        }
    }

    // all waves must finish reading this block's pixel rows before any store (WAR)
    __syncthreads();

    // epilogue: bias + silu, packed bf16 store to catT, fused pooling for co in [128,256)
    #pragma unroll
    for (int mt = 0; mt < 8; ++mt) {
        const int cobase = cohalf + mt * 16 + quad * 4;
        float bias[4];
        #pragma unroll
        for (int r = 0; r < 4; ++r) bias[r] = b1[cobase + r];
        float v[2][4];
        #pragma unroll
        for (int nt = 0; nt < 2; ++nt) {
            unsigned short pk[4];
            #pragma unroll
            for (int r = 0; r < 4; ++r) {
                v[nt][r] = silu_f(acc[mt][nt][r] + bias[r]);
                pk[r] = f2bf(v[nt][r]);
            }
            *(uint2*)&ct[(size_t)pp[nt] * 384 + cobase] = *(uint2*)pk;
        }
        if (cohalf == 128) {
            #pragma unroll
            for (int r = 0; r < 4; ++r) {
                float s = v[0][r] + v[1][r];
                #pragma unroll
                for (int m = 1; m < 16; m <<= 1)
                    s += __shfl_xor(s, m, 64);
                if (col == 0)
                    atomicAdd(&pooled[b * 128 + (cobase - 128) + r], s * (1.0f / NPIX));
            }
        }
    }
}

// ---------------- router: logits -> softmax -> top2 -> renorm ----------------
__global__ __launch_bounds__(64) void router_kernel(
    const float* __restrict__ pooled, const float* __restrict__ Wr,
    const float* __restrict__ br, int* __restrict__ sel_idx, float* __restrict__ sel_w)
{
    __shared__ float lg[16][4];
    int tid = threadIdx.x;
    int b = tid >> 2, e = tid & 3;
    float s = br[e];
    for (int c2 = 0; c2 < 128; c2++)
        s += pooled[b * 128 + c2] * Wr[e * 128 + c2];
    lg[b][e] = s;
    __syncthreads();
    if (tid < 16) {
        int bb = tid;
        float l[4]; float mx = -1e30f;
        #pragma unroll
        for (int i = 0; i < 4; i++) { l[i] = lg[bb][i]; mx = fmaxf(mx, l[i]); }
        float p[4]; float sum = 0.f;
        #pragma unroll
        for (int i = 0; i < 4; i++) { p[i] = __expf(l[i] - mx); sum += p[i]; }
        #pragma unroll
        for (int i = 0; i < 4; i++) p[i] /= sum;
        int i1 = 0;
        for (int i = 1; i < 4; i++) if (p[i] > p[i1]) i1 = i;
        int i2 = (i1 == 0) ? 1 : 0;
        for (int i = 0; i < 4; i++) if (i != i1 && p[i] > p[i2]) i2 = i;
        float inv = 1.0f / (p[i1] + p[i2]);
        sel_idx[bb * 2 + 0] = i1; sel_idx[bb * 2 + 1] = i2;
        sel_w[bb * 2 + 0] = p[i1] * inv; sel_w[bb * 2 + 1] = p[i2] * inv;
    }
}

// ---------------- expert conv as implicit GEMM w/ MFMA; B and output live in catT ---------
__global__ __launch_bounds__(256, 2) void expert_gemm(
    __hip_bfloat16* __restrict__ catT, const __hip_bfloat16* __restrict__ Wt,
    const float* __restrict__ bexp, const int* __restrict__ sel_idx,
    const float* __restrict__ sel_w)
{
    const int b  = blockIdx.y;
    const int p0 = blockIdx.x * 64;
    const int e0 = sel_idx[b * 2 + 0], e1 = sel_idx[b * 2 + 1];
    const float g0 = sel_w[b * 2 + 0], g1 = sel_w[b * 2 + 1];

    __shared__ short As[2][128][72];   // [expert][co][64 k + 8 pad] = 36864 B

    const int tid  = threadIdx.x;
    const int wave = tid >> 6, lane = tid & 63;
    const int col  = lane & 15, quad = lane >> 4;
    const int wco  = (wave >> 1) * 64;     // 0 / 64
    const int wpx  = (wave & 1) * 32;      // 0 / 32

    __hip_bfloat16* ct = catT + (size_t)b * NPIX * 384;
    const __hip_bfloat16* wsrc0 = Wt + (size_t)e0 * 128 * 1152;
    const __hip_bfloat16* wsrc1 = Wt + (size_t)e1 * 128 * 1152;

    int pp[2], prow[2], pcol[2];
    #pragma unroll
    for (int nt = 0; nt < 2; ++nt) {
        pp[nt]   = p0 + wpx + nt * 16 + col;
        prow[nt] = pp[nt] / IMW;
        pcol[nt] = pp[nt] % IMW;
    }

    floatx4 acc[2][4][2] = {};   // [expert][mt][nt]

    for (int ch = 0; ch < 18; ++ch) {
        const int tap = ch >> 1;
        const int cih = (ch & 1) << 6;          // 0 / 64
        __syncthreads();
        #pragma unroll
        for (int i = 0; i < 8; ++i) {
            int idx = tid + i * 256;            // 0..2047
            int e = idx >> 10;
            int rem = idx & 1023;
            int co = rem >> 3, kg = rem & 7;
            const __hip_bfloat16* src = (e == 0 ? wsrc0 : wsrc1)
                + (size_t)co * 1152 + tap * 128 + cih + kg * 8;
            *(int4*)&As[e][co][kg * 8] = *(const int4*)src;
        }
        __syncthreads();

        const int dyy = tap / 3 - 1, dxx = tap % 3 - 1;
        bool valid[2];
        const __hip_bfloat16* bbase[2];
        #pragma unroll
        for (int nt = 0; nt < 2; ++nt) {
            int ir = prow[nt] + dyy, ic = pcol[nt] + dxx;
            valid[nt] = ((unsigned)ir < IMH) && ((unsigned)ic < IMW);
            bbase[nt] = ct + (size_t)(ir * IMW + ic) * 384 + 128 + cih + quad * 8;
        }

        #pragma unroll
        for (int ks = 0; ks < 2; ++ks) {
            short8 bf[2];
            #pragma unroll
            for (int nt = 0; nt < 2; ++nt) {
                int4 vv = {0, 0, 0, 0};
                if (valid[nt]) vv = *(const int4*)(bbase[nt] + ks * 32);
                bf[nt] = *(short8*)&vv;
            }
            short8 af[2][4];
            #pragma unroll
            for (int e = 0; e < 2; ++e)
                #pragma unroll
                for (int mt = 0; mt < 4; ++mt)
                    af[e][mt] = *(const short8*)&As[e][wco + mt * 16 + col][ks * 32 + quad * 8];
            #pragma unroll
            for (int e = 0; e < 2; ++e)
                #pragma unroll
                for (int mt = 0; mt < 4; ++mt)
                    #pragma unroll
                    for (int nt = 0; nt < 2; ++nt)
                        acc[e][mt][nt] = __builtin_amdgcn_mfma_f32_16x16x32_bf16(
                            af[e][mt], bf[nt], acc[e][mt][nt], 0, 0, 0);
        }
    }

    // epilogue: bias + silu per expert, gate-weighted sum -> catT[pix][256+co] (bf16 packed)
    #pragma unroll
    for (int mt = 0; mt < 4; ++mt) {
        const int cobase = wco + mt * 16 + quad * 4;
        #pragma unroll
        for (int nt = 0; nt < 2; ++nt) {
            unsigned short pk[4];
            #pragma unroll
            for (int r = 0; r < 4; ++r) {
                int coo = cobase + r;
                float vb0 = bexp[e0 * 128 + coo];
                float vb1 = bexp[e1 * 128 + coo];
                float v = g0 * silu_f(acc[0][mt][nt][r] + vb0)
                        + g1 * silu_f(acc[1][mt][nt][r] + vb1);
                pk[r] = f2bf(v);
            }
            *(uint2*)&ct[(size_t)pp[nt] * 384 + 256 + cobase] = *(uint2*)pk;
        }
    }
}

// ---------------- cv2 as MFMA GEMM: out = silu(W2 @ catT^T + b2), fp32 NCHW out -----------
__global__ __launch_bounds__(256) void cv2_mfma(
    const __hip_bfloat16* __restrict__ catT, const __hip_bfloat16* __restrict__ Wt2,
    const float* __restrict__ b2, float* __restrict__ out)
{
    const int b  = blockIdx.y;
    const int p0 = blockIdx.x * 64;
    const int tid = threadIdx.x;
    const int wave = tid >> 6, lane = tid & 63;
    const int col = lane & 15, quad = lane >> 4;
    const int cohalf = (wave >> 1) * 128;
    const int wpx    = (wave & 1) * 32;

    const __hip_bfloat16* ct = catT + (size_t)b * NPIX * 384;
    int pp[2];
    pp[0] = p0 + wpx + col;
    pp[1] = pp[0] + 16;

    floatx4 acc[8][2] = {};

    for (int k0 = 0; k0 < 384; k0 += 32) {
        short8 bf[2];
        #pragma unroll
        for (int nt = 0; nt < 2; ++nt)
            bf[nt] = *(const short8*)&ct[(size_t)pp[nt] * 384 + k0 + quad * 8];
        #pragma unroll
        for (int mt = 0; mt < 8; ++mt) {
            short8 af = *(const short8*)&Wt2[(size_t)(cohalf + mt * 16 + col) * 384
                                             + k0 + quad * 8];
            acc[mt][0] = __builtin_amdgcn_mfma_f32_16x16x32_bf16(af, bf[0], acc[mt][0], 0, 0, 0);
            acc[mt][1] = __builtin_amdgcn_mfma_f32_16x16x32_bf16(af, bf[1], acc[mt][1], 0, 0, 0);
        }
    }

    #pragma unroll
    for (int mt = 0; mt < 8; ++mt) {
        const int cobase = cohalf + mt * 16 + quad * 4;
        #pragma unroll
        for (int r = 0; r < 4; ++r) {
            float bias = b2[cobase + r];
            size_t rowb = ((size_t)b * 256 + cobase + r) * NPIX;
            #pragma unroll
            for (int nt = 0; nt < 2; ++nt)
                out[rowb + pp[nt]] = silu_f(acc[mt][nt][r] + bias);
        }
    }
}

extern "C" void kernel_launch(void* const* d_in, const int* in_sizes, int n_in,
                              void* d_out, int out_size, void* d_ws, size_t ws_size,
                              hipStream_t stream)
{
    (void)in_sizes; (void)n_in; (void)out_size; (void)ws_size;
    const float* x    = (const float*)d_in[0];
    const float* W1   = (const float*)d_in[1];
    const float* b1   = (const float*)d_in[2];
    const float* Wr   = (const float*)d_in[3];
    const float* br   = (const float*)d_in[4];
    const float* Wexp = (const float*)d_in[5];
    const float* bexp = (const float*)d_in[6];
    const float* W2   = (const float*)d_in[7];
    const float* b2   = (const float*)d_in[8];
    float* out = (float*)d_out;

    char* ws = (char*)d_ws;
    __hip_bfloat16* catT = (__hip_bfloat16*)ws;                    // 78,643,200
    __hip_bfloat16* Wt   = (__hip_bfloat16*)(ws + 78643200);       //  1,179,648
    __hip_bfloat16* Wt1  = (__hip_bfloat16*)(ws + 79822848);       //    131,072
    __hip_bfloat16* Wt2  = (__hip_bfloat16*)(ws + 79953920);       //    196,608
    float* pooled        = (float*)(ws + 80150528);                //      8,192
    int*   sel_idx       = (int*)(ws + 80158720);                  //        128
    float* sel_w         = (float*)(ws + 80158848);                //        128

    hipMemsetAsync(pooled, 0, 16 * 128 * 4, stream);
    prep_small   <<<dim3(384),        256, 0, stream>>>(W1, W2, Wt1, Wt2);
    prep_wt      <<<dim3(256),        256, 0, stream>>>(Wexp, Wt);
    transpose_x  <<<dim3(100, 4, 16), 256, 0, stream>>>(x, catT);
    cv1_mfma     <<<dim3(100, 16),    256, 0, stream>>>(Wt1, b1, catT, pooled);
    router_kernel<<<1,                 64, 0, stream>>>(pooled, Wr, br, sel_idx, sel_w);
    expert_gemm  <<<dim3(100, 16),    256, 0, stream>>>(catT, Wt, bexp, sel_idx, sel_w);
    cv2_mfma     <<<dim3(100, 16),    256, 0, stream>>>(catT, Wt2, b2, out);
}

// Round 5
// 578.565 us; speedup vs baseline: 1.0347x; 1.0347x over previous
//
#include <hip/hip_runtime.h>
#include <hip/hip_bf16.h>

#define NPIX 6400
#define IMW 80
#define IMH 80

typedef __attribute__((ext_vector_type(8))) short short8;
typedef __attribute__((ext_vector_type(4))) float floatx4;

__device__ __forceinline__ float silu_f(float v) {
    return v / (1.0f + __expf(-v));
}
__device__ __forceinline__ unsigned short f2bf(float v) {
    __hip_bfloat16 h = __float2bfloat16(v);
    return *(unsigned short*)&h;
}

// ============ prep: swizzle weights into MFMA-fragment-contiguous layout ============
// layout: W[mtile][kstep][lane][8] bf16; lane=quad*16+col holds A[co=mt*16+col][k=ks*32+quad*8 ..+8]
// => one wave A-fragment load = 64 lanes x 16B CONTIGUOUS (1KB coalesced)

// W1 [256co][256k] -> Wt1s: 16 mt x 8 ks x 64 lane x 8
__global__ __launch_bounds__(256) void prep_swz1(
    const float* __restrict__ W1, __hip_bfloat16* __restrict__ Wt1s)
{
    int t = blockIdx.x * 256 + threadIdx.x;     // 8192 total
    int mt = t >> 9, rem = t & 511;
    int ks = rem >> 6, lane = rem & 63;
    int col = lane & 15, quad = lane >> 4;
    const float* src = W1 + (size_t)(mt * 16 + col) * 256 + ks * 32 + quad * 8;
    unsigned short pk[8];
    #pragma unroll
    for (int j = 0; j < 8; ++j) pk[j] = f2bf(src[j]);
    *(uint4*)(Wt1s + (size_t)t * 8) = *(uint4*)pk;
}

// W2 [256co][384k] -> Wt2s: 16 mt x 12 ks x 64 x 8
__global__ __launch_bounds__(256) void prep_swz2(
    const float* __restrict__ W2, __hip_bfloat16* __restrict__ Wt2s)
{
    int t = blockIdx.x * 256 + threadIdx.x;     // 12288 total
    int mt = t / 768, rem = t % 768;
    int ks = rem >> 6, lane = rem & 63;
    int col = lane & 15, quad = lane >> 4;
    const float* src = W2 + (size_t)(mt * 16 + col) * 384 + ks * 32 + quad * 8;
    unsigned short pk[8];
    #pragma unroll
    for (int j = 0; j < 8; ++j) pk[j] = f2bf(src[j]);
    *(uint4*)(Wt2s + (size_t)t * 8) = *(uint4*)pk;
}

// W_exp [e][co][ci][3][3] -> Wts: e x 8 gmt x 36 s x 64 x 8, where k = tap*128+ci,
// s = tap*4 + ci/32, frag k-offset = (s&3)*32 + quad*8
__global__ __launch_bounds__(256) void prep_swzE(
    const float* __restrict__ Wexp, __hip_bfloat16* __restrict__ Wts)
{
    int t = blockIdx.x * 256 + threadIdx.x;     // 73728 total
    int e = t / 18432, rem = t % 18432;
    int gmt = rem / 2304, rem2 = rem % 2304;
    int s = rem2 >> 6, lane = rem2 & 63;
    int col = lane & 15, quad = lane >> 4;
    int tap = s >> 2;
    int cib = (s & 3) * 32 + quad * 8;
    int co  = gmt * 16 + col;
    const float* src = Wexp + ((size_t)(e * 128 + co) * 128 + cib) * 9 + tap;
    unsigned short pk[8];
    #pragma unroll
    for (int j = 0; j < 8; ++j) pk[j] = f2bf(src[j * 9]);
    *(uint4*)(Wts + (size_t)t * 8) = *(uint4*)pk;
}

// ---------------- transpose x [b][ci][pix] fp32 -> catT[b][pix][ci] bf16 (slots 0..255) ----
__global__ __launch_bounds__(256) void transpose_x(
    const float* __restrict__ x, __hip_bfloat16* __restrict__ catT)
{
    const int b   = blockIdx.z;
    const int ci0 = blockIdx.y * 64;
    const int p0  = blockIdx.x * 64;
    __shared__ unsigned short t[64][70];
    const int tid = threadIdx.x;
    const float* src = x + ((size_t)b * 256 + ci0) * NPIX + p0;
    #pragma unroll
    for (int it = 0; it < 4; ++it) {
        int idx = tid + it * 256;          // 0..1023
        int ci = idx >> 4, pg = idx & 15;
        float4 v = *(const float4*)(src + (size_t)ci * NPIX + pg * 4);
        t[pg * 4 + 0][ci] = f2bf(v.x);
        t[pg * 4 + 1][ci] = f2bf(v.y);
        t[pg * 4 + 2][ci] = f2bf(v.z);
        t[pg * 4 + 3][ci] = f2bf(v.w);
    }
    __syncthreads();
    unsigned short* dst = (unsigned short*)catT + ((size_t)b * NPIX + p0) * 384 + ci0;
    #pragma unroll
    for (int it = 0; it < 2; ++it) {
        int idx = tid + it * 256;          // 0..511
        int p = idx >> 3, cg = idx & 7;
        unsigned short vv[8];
        #pragma unroll
        for (int j = 0; j < 8; ++j) vv[j] = t[p][cg * 8 + j];
        *(uint4*)(dst + (size_t)p * 384 + cg * 8) = *(uint4*)vv;
    }
}

// ---------------- cv1 as MFMA GEMM, in-place on catT --------------------------------------
// grid (100, 16), block 256 = 4 waves (2 co-halves x 2 pix-halves); K=256
__global__ __launch_bounds__(256) void cv1_mfma(
    const __hip_bfloat16* __restrict__ Wt1s, const float* __restrict__ b1,
    __hip_bfloat16* __restrict__ catT, float* __restrict__ pooled)
{
    const int b  = blockIdx.y;
    const int p0 = blockIdx.x * 64;
    const int tid = threadIdx.x;
    const int wave = tid >> 6, lane = tid & 63;
    const int col = lane & 15, quad = lane >> 4;
    const int cohalf = (wave >> 1) * 128;   // 0 / 128
    const int wpx    = (wave & 1) * 32;     // 0 / 32
    const int gmt0   = (wave >> 1) * 8;     // first mtile of this co-half

    __hip_bfloat16* ct = catT + (size_t)b * NPIX * 384;
    int pp[2];
    pp[0] = p0 + wpx + col;
    pp[1] = pp[0] + 16;

    floatx4 acc[8][2] = {};

    #pragma unroll
    for (int ks = 0; ks < 8; ++ks) {
        short8 bf[2];
        #pragma unroll
        for (int nt = 0; nt < 2; ++nt)
            bf[nt] = *(const short8*)&ct[(size_t)pp[nt] * 384 + ks * 32 + quad * 8];
        #pragma unroll
        for (int mt = 0; mt < 8; ++mt) {
            short8 af = *(const short8*)&Wt1s[(size_t)(((gmt0 + mt) * 8 + ks) * 64 + lane) * 8];
            acc[mt][0] = __builtin_amdgcn_mfma_f32_16x16x32_bf16(af, bf[0], acc[mt][0], 0, 0, 0);
            acc[mt][1] = __builtin_amdgcn_mfma_f32_16x16x32_bf16(af, bf[1], acc[mt][1], 0, 0, 0);
        }
    }

    // all waves must finish reading this block's pixel rows before any store (WAR)
    __syncthreads();

    #pragma unroll
    for (int mt = 0; mt < 8; ++mt) {
        const int cobase = cohalf + mt * 16 + quad * 4;
        float bias[4];
        #pragma unroll
        for (int r = 0; r < 4; ++r) bias[r] = b1[cobase + r];
        float v[2][4];
        #pragma unroll
        for (int nt = 0; nt < 2; ++nt) {
            unsigned short pk[4];
            #pragma unroll
            for (int r = 0; r < 4; ++r) {
                v[nt][r] = silu_f(acc[mt][nt][r] + bias[r]);
                pk[r] = f2bf(v[nt][r]);
            }
            *(uint2*)&ct[(size_t)pp[nt] * 384 + cobase] = *(uint2*)pk;
        }
        if (cohalf == 128) {
            #pragma unroll
            for (int r = 0; r < 4; ++r) {
                float s = v[0][r] + v[1][r];
                #pragma unroll
                for (int m = 1; m < 16; m <<= 1)
                    s += __shfl_xor(s, m, 64);
                if (col == 0)
                    atomicAdd(&pooled[b * 128 + (cobase - 128) + r], s * (1.0f / NPIX));
            }
        }
    }
}

// ---------------- router ----------------
__global__ __launch_bounds__(64) void router_kernel(
    const float* __restrict__ pooled, const float* __restrict__ Wr,
    const float* __restrict__ br, int* __restrict__ sel_idx, float* __restrict__ sel_w)
{
    __shared__ float lg[16][4];
    int tid = threadIdx.x;
    int b = tid >> 2, e = tid & 3;
    float s = br[e];
    for (int c2 = 0; c2 < 128; c2++)
        s += pooled[b * 128 + c2] * Wr[e * 128 + c2];
    lg[b][e] = s;
    __syncthreads();
    if (tid < 16) {
        int bb = tid;
        float l[4]; float mx = -1e30f;
        #pragma unroll
        for (int i = 0; i < 4; i++) { l[i] = lg[bb][i]; mx = fmaxf(mx, l[i]); }
        float p[4]; float sum = 0.f;
        #pragma unroll
        for (int i = 0; i < 4; i++) { p[i] = __expf(l[i] - mx); sum += p[i]; }
        #pragma unroll
        for (int i = 0; i < 4; i++) p[i] /= sum;
        int i1 = 0;
        for (int i = 1; i < 4; i++) if (p[i] > p[i1]) i1 = i;
        int i2 = (i1 == 0) ? 1 : 0;
        for (int i = 0; i < 4; i++) if (i != i1 && p[i] > p[i2]) i2 = i;
        float inv = 1.0f / (p[i1] + p[i2]);
        sel_idx[bb * 2 + 0] = i1; sel_idx[bb * 2 + 1] = i2;
        sel_w[bb * 2 + 0] = p[i1] * inv; sel_w[bb * 2 + 1] = p[i2] * inv;
    }
}

// ---------------- expert conv as implicit GEMM; no LDS, no barriers -----------------------
// grid (50 pixel-chunks of 128, 16 b); block 256 = 4 waves = 4 pixel-groups of 32
// wave: all 8 mtiles (128 co) x 2 ntiles(16pix) x 2 experts; K = 9 taps x 128 ci
__global__ __launch_bounds__(256, 2) void expert_gemm(
    __hip_bfloat16* __restrict__ catT, const __hip_bfloat16* __restrict__ Wts,
    const float* __restrict__ bexp, const int* __restrict__ sel_idx,
    const float* __restrict__ sel_w)
{
    const int b  = blockIdx.y;
    const int p0 = blockIdx.x * 128;
    const int e0 = sel_idx[b * 2 + 0], e1 = sel_idx[b * 2 + 1];
    const float g0 = sel_w[b * 2 + 0], g1 = sel_w[b * 2 + 1];

    const int tid  = threadIdx.x;
    const int wave = tid >> 6, lane = tid & 63;
    const int col  = lane & 15, quad = lane >> 4;

    __hip_bfloat16* ct = catT + (size_t)b * NPIX * 384;
    const __hip_bfloat16* wsrc[2];
    wsrc[0] = Wts + (size_t)e0 * 8 * 36 * 64 * 8 + (size_t)lane * 8;
    wsrc[1] = Wts + (size_t)e1 * 8 * 36 * 64 * 8 + (size_t)lane * 8;

    int pp[2], prow[2], pcol[2];
    #pragma unroll
    for (int nt = 0; nt < 2; ++nt) {
        pp[nt]   = p0 + wave * 32 + nt * 16 + col;
        prow[nt] = pp[nt] / IMW;
        pcol[nt] = pp[nt] % IMW;
    }

    floatx4 acc[2][8][2] = {};   // [expert][gmt][nt]

    for (int tap = 0; tap < 9; ++tap) {
        const int dyy = tap / 3 - 1, dxx = tap % 3 - 1;
        bool valid[2];
        const __hip_bfloat16* bbase[2];
        #pragma unroll
        for (int nt = 0; nt < 2; ++nt) {
            int ir = prow[nt] + dyy, ic = pcol[nt] + dxx;
            valid[nt] = ((unsigned)ir < IMH) && ((unsigned)ic < IMW);
            bbase[nt] = ct + (size_t)(ir * IMW + ic) * 384 + 128 + quad * 8;
        }
        #pragma unroll
        for (int ss = 0; ss < 4; ++ss) {
            const int s = tap * 4 + ss;
            short8 bf[2];
            #pragma unroll
            for (int nt = 0; nt < 2; ++nt) {
                int4 vv = {0, 0, 0, 0};
                if (valid[nt]) vv = *(const int4*)(bbase[nt] + ss * 32);
                bf[nt] = *(short8*)&vv;
            }
            #pragma unroll
            for (int e = 0; e < 2; ++e) {
                #pragma unroll
                for (int gmt = 0; gmt < 8; ++gmt) {
                    short8 af = *(const short8*)(wsrc[e] + (size_t)(gmt * 36 + s) * 64 * 8);
                    acc[e][gmt][0] = __builtin_amdgcn_mfma_f32_16x16x32_bf16(
                        af, bf[0], acc[e][gmt][0], 0, 0, 0);
                    acc[e][gmt][1] = __builtin_amdgcn_mfma_f32_16x16x32_bf16(
                        af, bf[1], acc[e][gmt][1], 0, 0, 0);
                }
            }
        }
    }

    // epilogue: bias + silu per expert, gate-weighted sum -> catT[pix][256+co]
    #pragma unroll
    for (int gmt = 0; gmt < 8; ++gmt) {
        const int cobase = gmt * 16 + quad * 4;
        #pragma unroll
        for (int nt = 0; nt < 2; ++nt) {
            unsigned short pk[4];
            #pragma unroll
            for (int r = 0; r < 4; ++r) {
                int coo = cobase + r;
                float vb0 = bexp[e0 * 128 + coo];
                float vb1 = bexp[e1 * 128 + coo];
                float v = g0 * silu_f(acc[0][gmt][nt][r] + vb0)
                        + g1 * silu_f(acc[1][gmt][nt][r] + vb1);
                pk[r] = f2bf(v);
            }
            *(uint2*)&ct[(size_t)pp[nt] * 384 + 256 + cobase] = *(uint2*)pk;
        }
    }
}

// ---------------- cv2 as MFMA GEMM: out = silu(W2 @ catT^T + b2), fp32 NCHW out -----------
__global__ __launch_bounds__(256) void cv2_mfma(
    const __hip_bfloat16* __restrict__ catT, const __hip_bfloat16* __restrict__ Wt2s,
    const float* __restrict__ b2, float* __restrict__ out)
{
    const int b  = blockIdx.y;
    const int p0 = blockIdx.x * 64;
    const int tid = threadIdx.x;
    const int wave = tid >> 6, lane = tid & 63;
    const int col = lane & 15, quad = lane >> 4;
    const int cohalf = (wave >> 1) * 128;
    const int wpx    = (wave & 1) * 32;
    const int gmt0   = (wave >> 1) * 8;

    const __hip_bfloat16* ct = catT + (size_t)b * NPIX * 384;
    int pp[2];
    pp[0] = p0 + wpx + col;
    pp[1] = pp[0] + 16;

    floatx4 acc[8][2] = {};

    #pragma unroll
    for (int ks = 0; ks < 12; ++ks) {
        short8 bf[2];
        #pragma unroll
        for (int nt = 0; nt < 2; ++nt)
            bf[nt] = *(const short8*)&ct[(size_t)pp[nt] * 384 + ks * 32 + quad * 8];
        #pragma unroll
        for (int mt = 0; mt < 8; ++mt) {
            short8 af = *(const short8*)&Wt2s[(size_t)(((gmt0 + mt) * 12 + ks) * 64 + lane) * 8];
            acc[mt][0] = __builtin_amdgcn_mfma_f32_16x16x32_bf16(af, bf[0], acc[mt][0], 0, 0, 0);
            acc[mt][1] = __builtin_amdgcn_mfma_f32_16x16x32_bf16(af, bf[1], acc[mt][1], 0, 0, 0);
        }
    }

    #pragma unroll
    for (int mt = 0; mt < 8; ++mt) {
        const int cobase = cohalf + mt * 16 + quad * 4;
        #pragma unroll
        for (int r = 0; r < 4; ++r) {
            float bias = b2[cobase + r];
            size_t rowb = ((size_t)b * 256 + cobase + r) * NPIX;
            #pragma unroll
            for (int nt = 0; nt < 2; ++nt)
                out[rowb + pp[nt]] = silu_f(acc[mt][nt][r] + bias);
        }
    }
}

extern "C" void kernel_launch(void* const* d_in, const int* in_sizes, int n_in,
                              void* d_out, int out_size, void* d_ws, size_t ws_size,
                              hipStream_t stream)
{
    (void)in_sizes; (void)n_in; (void)out_size; (void)ws_size;
    const float* x    = (const float*)d_in[0];
    const float* W1   = (const float*)d_in[1];
    const float* b1   = (const float*)d_in[2];
    const float* Wr   = (const float*)d_in[3];
    const float* br   = (const float*)d_in[4];
    const float* Wexp = (const float*)d_in[5];
    const float* bexp = (const float*)d_in[6];
    const float* W2   = (const float*)d_in[7];
    const float* b2   = (const float*)d_in[8];
    float* out = (float*)d_out;

    char* ws = (char*)d_ws;
    __hip_bfloat16* catT = (__hip_bfloat16*)ws;                    // 78,643,200
    __hip_bfloat16* Wts  = (__hip_bfloat16*)(ws + 78643200);       //  1,179,648
    __hip_bfloat16* Wt1s = (__hip_bfloat16*)(ws + 79822848);       //    131,072
    __hip_bfloat16* Wt2s = (__hip_bfloat16*)(ws + 79953920);       //    196,608
    float* pooled        = (float*)(ws + 80150528);                //      8,192
    int*   sel_idx       = (int*)(ws + 80158720);                  //        128
    float* sel_w         = (float*)(ws + 80158848);                //        128

    hipMemsetAsync(pooled, 0, 16 * 128 * 4, stream);
    prep_swz1    <<<dim3(32),         256, 0, stream>>>(W1, Wt1s);
    prep_swz2    <<<dim3(48),         256, 0, stream>>>(W2, Wt2s);
    prep_swzE    <<<dim3(288),        256, 0, stream>>>(Wexp, Wts);
    transpose_x  <<<dim3(100, 4, 16), 256, 0, stream>>>(x, catT);
    cv1_mfma     <<<dim3(100, 16),    256, 0, stream>>>(Wt1s, b1, catT, pooled);
    router_kernel<<<1,                 64, 0, stream>>>(pooled, Wr, br, sel_idx, sel_w);
    expert_gemm  <<<dim3(50, 16),     256, 0, stream>>>(catT, Wts, bexp, sel_idx, sel_w);
    cv2_mfma     <<<dim3(100, 16),    256, 0, stream>>>(catT, Wt2s, b2, out);
}

// Round 6
// 472.969 us; speedup vs baseline: 1.2657x; 1.2233x over previous
//
#include <hip/hip_runtime.h>
#include <hip/hip_bf16.h>

#define NPIX 6400
#define IMW 80
#define IMH 80

typedef __attribute__((ext_vector_type(8))) short short8;
typedef __attribute__((ext_vector_type(4))) float floatx4;

__device__ __forceinline__ float silu_f(float v) {
    return v / (1.0f + __expf(-v));
}
__device__ __forceinline__ unsigned short f2bf(float v) {
    __hip_bfloat16 h = __float2bfloat16(v);
    return *(unsigned short*)&h;
}

// ============ prep: swizzle weights into MFMA-fragment-contiguous layout ============
// layout: W[mtile][kstep][lane][8] bf16; lane=quad*16+col holds A[co=mt*16+col][k=ks*32+quad*8 ..+8]

// W1 [256co][256k] -> Wt1s: 16 mt x 8 ks x 64 lane x 8
__global__ __launch_bounds__(256) void prep_swz1(
    const float* __restrict__ W1, __hip_bfloat16* __restrict__ Wt1s)
{
    int t = blockIdx.x * 256 + threadIdx.x;     // 8192 total
    int mt = t >> 9, rem = t & 511;
    int ks = rem >> 6, lane = rem & 63;
    int col = lane & 15, quad = lane >> 4;
    const float* src = W1 + (size_t)(mt * 16 + col) * 256 + ks * 32 + quad * 8;
    unsigned short pk[8];
    #pragma unroll
    for (int j = 0; j < 8; ++j) pk[j] = f2bf(src[j]);
    *(uint4*)(Wt1s + (size_t)t * 8) = *(uint4*)pk;
}

// W2 [256co][384k] -> Wt2s: 16 mt x 12 ks x 64 x 8
__global__ __launch_bounds__(256) void prep_swz2(
    const float* __restrict__ W2, __hip_bfloat16* __restrict__ Wt2s)
{
    int t = blockIdx.x * 256 + threadIdx.x;     // 12288 total
    int mt = t / 768, rem = t % 768;
    int ks = rem >> 6, lane = rem & 63;
    int col = lane & 15, quad = lane >> 4;
    const float* src = W2 + (size_t)(mt * 16 + col) * 384 + ks * 32 + quad * 8;
    unsigned short pk[8];
    #pragma unroll
    for (int j = 0; j < 8; ++j) pk[j] = f2bf(src[j]);
    *(uint4*)(Wt2s + (size_t)t * 8) = *(uint4*)pk;
}

// W_exp [e][co][ci][3][3] -> Wts: e x 8 gmt x 36 s x 64 x 8; s = tap*4 + ci/32
__global__ __launch_bounds__(256) void prep_swzE(
    const float* __restrict__ Wexp, __hip_bfloat16* __restrict__ Wts)
{
    int t = blockIdx.x * 256 + threadIdx.x;     // 73728 total
    int e = t / 18432, rem = t % 18432;
    int gmt = rem / 2304, rem2 = rem % 2304;
    int s = rem2 >> 6, lane = rem2 & 63;
    int col = lane & 15, quad = lane >> 4;
    int tap = s >> 2;
    int cib = (s & 3) * 32 + quad * 8;
    int co  = gmt * 16 + col;
    const float* src = Wexp + ((size_t)(e * 128 + co) * 128 + cib) * 9 + tap;
    unsigned short pk[8];
    #pragma unroll
    for (int j = 0; j < 8; ++j) pk[j] = f2bf(src[j * 9]);
    *(uint4*)(Wts + (size_t)t * 8) = *(uint4*)pk;
}

// ---------------- transpose x [b][ci][pix] fp32 -> catT[b][pix][ci] bf16 (slots 0..255) ----
__global__ __launch_bounds__(256) void transpose_x(
    const float* __restrict__ x, __hip_bfloat16* __restrict__ catT)
{
    const int b   = blockIdx.z;
    const int ci0 = blockIdx.y * 64;
    const int p0  = blockIdx.x * 64;
    __shared__ unsigned short t[64][70];
    const int tid = threadIdx.x;
    const float* src = x + ((size_t)b * 256 + ci0) * NPIX + p0;
    #pragma unroll
    for (int it = 0; it < 4; ++it) {
        int idx = tid + it * 256;          // 0..1023
        int ci = idx >> 4, pg = idx & 15;
        float4 v = *(const float4*)(src + (size_t)ci * NPIX + pg * 4);
        t[pg * 4 + 0][ci] = f2bf(v.x);
        t[pg * 4 + 1][ci] = f2bf(v.y);
        t[pg * 4 + 2][ci] = f2bf(v.z);
        t[pg * 4 + 3][ci] = f2bf(v.w);
    }
    __syncthreads();
    unsigned short* dst = (unsigned short*)catT + ((size_t)b * NPIX + p0) * 384 + ci0;
    #pragma unroll
    for (int it = 0; it < 2; ++it) {
        int idx = tid + it * 256;          // 0..511
        int p = idx >> 3, cg = idx & 7;
        unsigned short vv[8];
        #pragma unroll
        for (int j = 0; j < 8; ++j) vv[j] = t[p][cg * 8 + j];
        *(uint4*)(dst + (size_t)p * 384 + cg * 8) = *(uint4*)vv;
    }
}

// ---------------- cv1 as MFMA GEMM, in-place on catT --------------------------------------
// grid (50, 16), block 256 = 4 waves (2 co-halves x 2 pix-halves); wave = 8mt x 4nt; K=256
__global__ __launch_bounds__(256, 2) void cv1_mfma(
    const __hip_bfloat16* __restrict__ Wt1s, const float* __restrict__ b1,
    __hip_bfloat16* __restrict__ catT, float* __restrict__ pooled)
{
    const int b  = blockIdx.y;
    const int p0 = blockIdx.x * 128;
    const int tid = threadIdx.x;
    const int wave = tid >> 6, lane = tid & 63;
    const int col = lane & 15, quad = lane >> 4;
    const int cohalf  = (wave & 1) * 128;
    const int gmt0    = (wave & 1) * 8;
    const int pixhalf = (wave >> 1) * 64;

    __hip_bfloat16* ct = catT + (size_t)b * NPIX * 384;
    int pp[4];
    #pragma unroll
    for (int nt = 0; nt < 4; ++nt) pp[nt] = p0 + pixhalf + nt * 16 + col;

    floatx4 acc[8][4] = {};

    #pragma unroll
    for (int ks = 0; ks < 8; ++ks) {
        short8 bf[4];
        #pragma unroll
        for (int nt = 0; nt < 4; ++nt)
            bf[nt] = *(const short8*)&ct[(size_t)pp[nt] * 384 + ks * 32 + quad * 8];
        #pragma unroll
        for (int mt = 0; mt < 8; ++mt) {
            short8 af = *(const short8*)&Wt1s[(size_t)(((gmt0 + mt) * 8 + ks) * 64 + lane) * 8];
            #pragma unroll
            for (int nt = 0; nt < 4; ++nt)
                acc[mt][nt] = __builtin_amdgcn_mfma_f32_16x16x32_bf16(af, bf[nt], acc[mt][nt], 0, 0, 0);
        }
    }

    // all waves must finish reading this block's pixel rows before any store (WAR)
    __syncthreads();

    #pragma unroll
    for (int mt = 0; mt < 8; ++mt) {
        const int cobase = cohalf + mt * 16 + quad * 4;
        float bias[4];
        #pragma unroll
        for (int r = 0; r < 4; ++r) bias[r] = b1[cobase + r];
        float v[4][4];
        #pragma unroll
        for (int nt = 0; nt < 4; ++nt) {
            unsigned short pk[4];
            #pragma unroll
            for (int r = 0; r < 4; ++r) {
                v[nt][r] = silu_f(acc[mt][nt][r] + bias[r]);
                pk[r] = f2bf(v[nt][r]);
            }
            *(uint2*)&ct[(size_t)pp[nt] * 384 + cobase] = *(uint2*)pk;
        }
        if (cohalf == 128) {
            #pragma unroll
            for (int r = 0; r < 4; ++r) {
                float s = v[0][r] + v[1][r] + v[2][r] + v[3][r];
                #pragma unroll
                for (int m = 1; m < 16; m <<= 1)
                    s += __shfl_xor(s, m, 64);
                if (col == 0)
                    atomicAdd(&pooled[b * 128 + (cobase - 128) + r], s * (1.0f / NPIX));
            }
        }
    }
}

// ---------------- router ----------------
__global__ __launch_bounds__(64) void router_kernel(
    const float* __restrict__ pooled, const float* __restrict__ Wr,
    const float* __restrict__ br, int* __restrict__ sel_idx, float* __restrict__ sel_w)
{
    __shared__ float lg[16][4];
    int tid = threadIdx.x;
    int b = tid >> 2, e = tid & 3;
    float s = br[e];
    for (int c2 = 0; c2 < 128; c2++)
        s += pooled[b * 128 + c2] * Wr[e * 128 + c2];
    lg[b][e] = s;
    __syncthreads();
    if (tid < 16) {
        int bb = tid;
        float l[4]; float mx = -1e30f;
        #pragma unroll
        for (int i = 0; i < 4; i++) { l[i] = lg[bb][i]; mx = fmaxf(mx, l[i]); }
        float p[4]; float sum = 0.f;
        #pragma unroll
        for (int i = 0; i < 4; i++) { p[i] = __expf(l[i] - mx); sum += p[i]; }
        #pragma unroll
        for (int i = 0; i < 4; i++) p[i] /= sum;
        int i1 = 0;
        for (int i = 1; i < 4; i++) if (p[i] > p[i1]) i1 = i;
        int i2 = (i1 == 0) ? 1 : 0;
        for (int i = 0; i < 4; i++) if (i != i1 && p[i] > p[i2]) i2 = i;
        float inv = 1.0f / (p[i1] + p[i2]);
        sel_idx[bb * 2 + 0] = i1; sel_idx[bb * 2 + 1] = i2;
        sel_w[bb * 2 + 0] = p[i1] * inv; sel_w[bb * 2 + 1] = p[i2] * inv;
    }
}

// ---------------- expert conv as implicit GEMM; no LDS, no barriers -----------------------
// grid (50, 16), block 256 = 4 waves (2 co-halves x 2 pix-halves)
// wave: 4 mt(16co) x 4 nt(16pix) x 2 experts; K = 9 taps x 128 ci
__global__ __launch_bounds__(256, 2) void expert_gemm(
    __hip_bfloat16* __restrict__ catT, const __hip_bfloat16* __restrict__ Wts,
    const float* __restrict__ bexp, const int* __restrict__ sel_idx,
    const float* __restrict__ sel_w)
{
    const int b  = blockIdx.y;
    const int p0 = blockIdx.x * 128;
    const int e0 = sel_idx[b * 2 + 0], e1 = sel_idx[b * 2 + 1];
    const float g0 = sel_w[b * 2 + 0], g1 = sel_w[b * 2 + 1];

    const int tid  = threadIdx.x;
    const int wave = tid >> 6, lane = tid & 63;
    const int col  = lane & 15, quad = lane >> 4;
    const int cohalf  = (wave & 1) * 64;
    const int gmt0    = (wave & 1) * 4;
    const int pixhalf = (wave >> 1) * 64;

    __hip_bfloat16* ct = catT + (size_t)b * NPIX * 384;
    const __hip_bfloat16* wsrc[2];
    wsrc[0] = Wts + (size_t)e0 * 8 * 36 * 64 * 8 + (size_t)lane * 8;
    wsrc[1] = Wts + (size_t)e1 * 8 * 36 * 64 * 8 + (size_t)lane * 8;

    int pp[4], prow[4], pcol[4];
    #pragma unroll
    for (int nt = 0; nt < 4; ++nt) {
        pp[nt]   = p0 + pixhalf + nt * 16 + col;
        prow[nt] = pp[nt] / IMW;
        pcol[nt] = pp[nt] % IMW;
    }

    floatx4 acc[2][4][4] = {};   // [expert][mt][nt]

    for (int tap = 0; tap < 9; ++tap) {
        const int dyy = tap / 3 - 1, dxx = tap % 3 - 1;
        bool valid[4];
        const __hip_bfloat16* bbase[4];
        #pragma unroll
        for (int nt = 0; nt < 4; ++nt) {
            int ir = prow[nt] + dyy, ic = pcol[nt] + dxx;
            valid[nt] = ((unsigned)ir < IMH) && ((unsigned)ic < IMW);
            bbase[nt] = ct + (size_t)(ir * IMW + ic) * 384 + 128 + quad * 8;
        }
        #pragma unroll
        for (int ss = 0; ss < 4; ++ss) {
            const int s = tap * 4 + ss;
            short8 bf[4];
            #pragma unroll
            for (int nt = 0; nt < 4; ++nt) {
                int4 vv = {0, 0, 0, 0};
                if (valid[nt]) vv = *(const int4*)(bbase[nt] + ss * 32);
                bf[nt] = *(short8*)&vv;
            }
            #pragma unroll
            for (int e = 0; e < 2; ++e) {
                #pragma unroll
                for (int mt = 0; mt < 4; ++mt) {
                    short8 af = *(const short8*)(wsrc[e] + (size_t)((gmt0 + mt) * 36 + s) * 64 * 8);
                    #pragma unroll
                    for (int nt = 0; nt < 4; ++nt)
                        acc[e][mt][nt] = __builtin_amdgcn_mfma_f32_16x16x32_bf16(
                            af, bf[nt], acc[e][mt][nt], 0, 0, 0);
                }
            }
        }
    }

    // epilogue: bias + silu per expert, gate-weighted sum -> catT[pix][256+co]
    #pragma unroll
    for (int mt = 0; mt < 4; ++mt) {
        const int cobase = cohalf + mt * 16 + quad * 4;
        #pragma unroll
        for (int nt = 0; nt < 4; ++nt) {
            unsigned short pk[4];
            #pragma unroll
            for (int r = 0; r < 4; ++r) {
                int coo = cobase + r;
                float vb0 = bexp[e0 * 128 + coo];
                float vb1 = bexp[e1 * 128 + coo];
                float v = g0 * silu_f(acc[0][mt][nt][r] + vb0)
                        + g1 * silu_f(acc[1][mt][nt][r] + vb1);
                pk[r] = f2bf(v);
            }
            *(uint2*)&ct[(size_t)pp[nt] * 384 + 256 + cobase] = *(uint2*)pk;
        }
    }
}

// ---------------- cv2 as MFMA GEMM: out = silu(W2 @ catT^T + b2), fp32 NCHW out -----------
// grid (50, 16), block 256 = 4 waves (2 co-halves x 2 pix-halves); wave = 8mt x 4nt; K=384
__global__ __launch_bounds__(256, 2) void cv2_mfma(
    const __hip_bfloat16* __restrict__ catT, const __hip_bfloat16* __restrict__ Wt2s,
    const float* __restrict__ b2, float* __restrict__ out)
{
    const int b  = blockIdx.y;
    const int p0 = blockIdx.x * 128;
    const int tid = threadIdx.x;
    const int wave = tid >> 6, lane = tid & 63;
    const int col = lane & 15, quad = lane >> 4;
    const int cohalf  = (wave & 1) * 128;
    const int gmt0    = (wave & 1) * 8;
    const int pixhalf = (wave >> 1) * 64;

    const __hip_bfloat16* ct = catT + (size_t)b * NPIX * 384;
    int pp[4];
    #pragma unroll
    for (int nt = 0; nt < 4; ++nt) pp[nt] = p0 + pixhalf + nt * 16 + col;

    floatx4 acc[8][4] = {};

    #pragma unroll
    for (int ks = 0; ks < 12; ++ks) {
        short8 bf[4];
        #pragma unroll
        for (int nt = 0; nt < 4; ++nt)
            bf[nt] = *(const short8*)&ct[(size_t)pp[nt] * 384 + ks * 32 + quad * 8];
        #pragma unroll
        for (int mt = 0; mt < 8; ++mt) {
            short8 af = *(const short8*)&Wt2s[(size_t)(((gmt0 + mt) * 12 + ks) * 64 + lane) * 8];
            #pragma unroll
            for (int nt = 0; nt < 4; ++nt)
                acc[mt][nt] = __builtin_amdgcn_mfma_f32_16x16x32_bf16(af, bf[nt], acc[mt][nt], 0, 0, 0);
        }
    }

    #pragma unroll
    for (int mt = 0; mt < 8; ++mt) {
        const int cobase = cohalf + mt * 16 + quad * 4;
        #pragma unroll
        for (int r = 0; r < 4; ++r) {
            float bias = b2[cobase + r];
            size_t rowb = ((size_t)b * 256 + cobase + r) * NPIX;
            #pragma unroll
            for (int nt = 0; nt < 4; ++nt)
                out[rowb + pp[nt]] = silu_f(acc[mt][nt][r] + bias);
        }
    }
}

extern "C" void kernel_launch(void* const* d_in, const int* in_sizes, int n_in,
                              void* d_out, int out_size, void* d_ws, size_t ws_size,
                              hipStream_t stream)
{
    (void)in_sizes; (void)n_in; (void)out_size; (void)ws_size;
    const float* x    = (const float*)d_in[0];
    const float* W1   = (const float*)d_in[1];
    const float* b1   = (const float*)d_in[2];
    const float* Wr   = (const float*)d_in[3];
    const float* br   = (const float*)d_in[4];
    const float* Wexp = (const float*)d_in[5];
    const float* bexp = (const float*)d_in[6];
    const float* W2   = (const float*)d_in[7];
    const float* b2   = (const float*)d_in[8];
    float* out = (float*)d_out;

    char* ws = (char*)d_ws;
    __hip_bfloat16* catT = (__hip_bfloat16*)ws;                    // 78,643,200
    __hip_bfloat16* Wts  = (__hip_bfloat16*)(ws + 78643200);       //  1,179,648
    __hip_bfloat16* Wt1s = (__hip_bfloat16*)(ws + 79822848);       //    131,072
    __hip_bfloat16* Wt2s = (__hip_bfloat16*)(ws + 79953920);       //    196,608
    float* pooled        = (float*)(ws + 80150528);                //      8,192
    int*   sel_idx       = (int*)(ws + 80158720);                  //        128
    float* sel_w         = (float*)(ws + 80158848);                //        128

    hipMemsetAsync(pooled, 0, 16 * 128 * 4, stream);
    prep_swz1    <<<dim3(32),         256, 0, stream>>>(W1, Wt1s);
    prep_swz2    <<<dim3(48),         256, 0, stream>>>(W2, Wt2s);
    prep_swzE    <<<dim3(288),        256, 0, stream>>>(Wexp, Wts);
    transpose_x  <<<dim3(100, 4, 16), 256, 0, stream>>>(x, catT);
    cv1_mfma     <<<dim3(50, 16),     256, 0, stream>>>(Wt1s, b1, catT, pooled);
    router_kernel<<<1,                 64, 0, stream>>>(pooled, Wr, br, sel_idx, sel_w);
    expert_gemm  <<<dim3(50, 16),     256, 0, stream>>>(catT, Wts, bexp, sel_idx, sel_w);
    cv2_mfma     <<<dim3(50, 16),     256, 0, stream>>>(catT, Wt2s, b2, out);
}